// Round 4
// baseline (5625.410 us; speedup 1.0000x reference)
//
#include <hip/hip_runtime.h>
#include <hip/hip_fp16.h>

namespace {

typedef _Float16 f16;
typedef __attribute__((ext_vector_type(8))) _Float16 f16x8;
typedef __attribute__((ext_vector_type(4))) float f32x4;

constexpr int kIn    = 64;
constexpr int kHid   = 128;
constexpr int kOut   = 64;
constexpr int kT     = 1000;
constexpr int kBatch = 256;
constexpr int kRows  = 16;   // batch rows per block (MFMA M dimension)

__device__ __forceinline__ float sigm(float v)  { return 1.0f / (1.0f + __expf(-v)); }
__device__ __forceinline__ float tanh_(float v) { return 2.0f / (1.0f + __expf(-2.0f * v)) - 1.0f; }

__device__ __forceinline__ f32x4 zero4() { f32x4 v; v[0]=0.f; v[1]=0.f; v[2]=0.f; v[3]=0.f; return v; }

__device__ __forceinline__ f32x4 mm(f16x8 a, f16x8 b, f32x4 c) {
  return __builtin_amdgcn_mfma_f32_16x16x32_f16(a, b, c, 0, 0, 0);
}

// 16 rows/block: activations in LDS as [16][K] f16, 16B-chunk XOR-swizzled by row
// (rows are 512B/256B apart -> same banks without swizzle; c^=row&7 spreads 8 ways,
//  2 lanes/bank = free per m136).
__device__ __forceinline__ int fr256(int row, int chunk) { return row*256 + ((chunk ^ (row & 7)) << 3); }
__device__ __forceinline__ int fr128(int row, int chunk) { return row*128 + ((chunk ^ (row & 7)) << 3); }
__device__ __forceinline__ int el256(int row, int k) { return row*256 + ((((k >> 3) ^ (row & 7)) << 3) | (k & 7)); }
__device__ __forceinline__ int el128(int row, int k) { return row*128 + ((((k >> 3) ^ (row & 7)) << 3) | (k & 7)); }

// 16 blocks x 256 threads (4 waves, 1 wave/EU -> 512-VGPR budget).
// Wave w owns hidden cols [32w, 32w+32) of every matvec; all per-(row,j) epilogue
// math is lane-local (D-layout: col=lane&15, row=(lane>>4)*4+reg, verified m89).
// Per step: ALPHA {z,r,HA MFMAs (hi+lo split), y(t-1) MFMA} -> BETA {gates, srh
// publish, y store} -> B1 -> {HH MFMA, dgh/dgx(t+1) MFMA} -> GAMMA {h update,
// publish ghh(t+1)/x'(t+1)/h(t)} -> B2.  2 barriers, 2 LDS round-trips.
__global__ __attribute__((amdgpu_flat_work_group_size(256, 256),
                          amdgpu_waves_per_eu(1, 1)))
void grud_mfma(
    const float* __restrict__ gIn,
    const float* __restrict__ xMean,
    const float* __restrict__ Wdgx, const float* __restrict__ bdgx,
    const float* __restrict__ Wdgh, const float* __restrict__ bdgh,
    const float* __restrict__ Wxz,  const float* __restrict__ Whz,
    const float* __restrict__ Wmz,  const float* __restrict__ bmz,
    const float* __restrict__ Wxr,  const float* __restrict__ Whr,
    const float* __restrict__ Wmr,
    const float* __restrict__ Wxh,  const float* __restrict__ Whh,
    const float* __restrict__ Wmh,  const float* __restrict__ bmh,
    const float* __restrict__ Why,  const float* __restrict__ bhy,
    float* __restrict__ out)
{
  // activation LDS: [x'|m|gh*h] K=256 (hi+lo split), srh K=128 (hi), h K=128 (hi)
  __shared__ __align__(16) f16 aZRh[kRows * 256];
  __shared__ __align__(16) f16 aZRl[kRows * 256];
  __shared__ __align__(16) f16 aSRH[kRows * 128];
  __shared__ __align__(16) f16 aH  [kRows * 128];

  const int tid = threadIdx.x;
  const int w   = tid >> 6;        // wave 0..3
  const int l   = tid & 63;
  const int lr  = l & 15;          // fragment row/col index
  const int kg  = l >> 4;          // k-group 0..3
  const int b0  = blockIdx.x * kRows;

  // ---------- B-fragments (weights) in VGPRs: B[k][j], lane holds col j=jb+lr,
  // k = kb + kg*8 + e ----------
  auto ldB = [&](const float* W, int N, int kb, int jb) {
    f16x8 v;
#pragma unroll
    for (int e = 0; e < 8; ++e) v[e] = (f16)W[(kb + kg * 8 + e) * N + jb + lr];
    return v;
  };

  f16x8 wz[2][8], wr_[2][8], wha[2][4], whh[2][4], wdgh[2][2], wdgx[2], why_[4];
#pragma unroll
  for (int tz = 0; tz < 2; ++tz) {
    const int jb = 32 * w + 16 * tz;
#pragma unroll
    for (int ks = 0; ks < 8; ++ks) {           // z/r: K=256 concat [x'|m|gh*h]
      const int kb = ks * 32;
      const float* Wzp = (kb < 64) ? Wxz : ((kb < 128) ? Wmz : Whz);
      const float* Wrp = (kb < 64) ? Wxr : ((kb < 128) ? Wmr : Whr);
      const int ko = (kb < 64) ? kb : ((kb < 128) ? (kb - 64) : (kb - 128));
      wz [tz][ks] = ldB(Wzp, kHid, ko, jb);
      wr_[tz][ks] = ldB(Wrp, kHid, ko, jb);
    }
#pragma unroll
    for (int ks = 0; ks < 4; ++ks) {           // HA: K=128 concat [x'|m]; HH: K=128
      const int kb = ks * 32;
      wha[tz][ks] = ldB((kb < 64) ? Wxh : Wmh, kHid, (kb < 64) ? kb : (kb - 64), jb);
      whh[tz][ks] = ldB(Whh, kHid, kb, jb);
    }
    wdgh[tz][0] = ldB(Wdgh, kHid, 0,  jb);     // dgh: K=64
    wdgh[tz][1] = ldB(Wdgh, kHid, 32, jb);
  }
  wdgx[0] = ldB(Wdgx, kIn, 0,  16 * w);        // dgx: K=64, N=64 (tile w)
  wdgx[1] = ldB(Wdgx, kIn, 32, 16 * w);
#pragma unroll
  for (int ks = 0; ks < 4; ++ks) why_[ks] = ldB(Why, kOut, ks * 32, 16 * w);  // y: K=128, N=64

  // ---------- lane-local constants ----------
  const int   j0 = 32 * w + lr, j1 = j0 + 16;
  const float bz[2]  = {bmz[j0],  bmz[j1]};
  const float bh[2]  = {bmh[j0],  bmh[j1]};
  const float bgh[2] = {bdgh[j0], bdgh[j1]};
  const int   cy  = 16 * w + lr;               // x'/y column this lane owns
  const float by  = bhy[cy], bgx = bdgx[cy], xmn = xMean[cy];

  const size_t dBase = ((size_t)(b0 + lr) * 3 + 2) * (size_t)(kIn * kT);
  size_t xB[4], mB[4], yB[4], hB[4];
#pragma unroll
  for (int rr = 0; rr < 4; ++rr) {
    const int row = kg * 4 + rr;
    xB[rr] = ((size_t)(b0 + row) * 3 + 0) * (size_t)(kIn * kT) + (size_t)cy * kT;
    mB[rr] = ((size_t)(b0 + row) * 3 + 1) * (size_t)(kIn * kT) + (size_t)cy * kT;
    yB[rr] = (size_t)(b0 + row) * kT * kOut + cy;
    hB[rr] = (size_t)kBatch * kT * kOut + (size_t)(b0 + row) * kT * kHid;
  }

  // zero LDS (covers ghh(0)=0 and the always-zero m-lo section)
  for (int i = tid; i < kRows * 256; i += 256) { aZRh[i] = (f16)0.f; aZRl[i] = (f16)0.f; }
  for (int i = tid; i < kRows * 128; i += 256) { aSRH[i] = (f16)0.f; aH[i] = (f16)0.f; }
  __syncthreads();

  float ghh[2][4] = {};   // gh(t)*h(t-1) for owned (tile,row) — lane-local state
  float xl[4]     = {};   // last-observed x for owned (row, cy)

  // ---------- prologue: x'(0), m(0) ----------
  {
    float dv[16];
#pragma unroll
    for (int q = 0; q < 2; ++q)
#pragma unroll
      for (int e = 0; e < 8; ++e) dv[q * 8 + e] = gIn[dBase + (size_t)(q * 32 + kg * 8 + e) * kT];
    f16x8 fd[2];
#pragma unroll
    for (int q = 0; q < 2; ++q)
#pragma unroll
      for (int e = 0; e < 8; ++e) fd[q][e] = (f16)dv[q * 8 + e];
    f32x4 aX = zero4();
    aX = mm(fd[0], wdgx[0], aX);
    aX = mm(fd[1], wdgx[1], aX);
#pragma unroll
    for (int rr = 0; rr < 4; ++rr) {
      const int row = kg * 4 + rr;
      const float xv = gIn[xB[rr]], mv = gIn[mB[rr]];
      const float gx = __expf(-fmaxf(aX[rr] + bgx, 0.f));
      xl[rr] = (mv > 0.f) ? xv : 0.f;
      const float xp = mv * xv + (1.f - mv) * (gx * xl[rr] + (1.f - gx) * xmn);
      const f16 xh = (f16)xp;
      aZRh[el256(row, cy)]      = xh;
      aZRl[el256(row, cy)]      = (f16)(xp - (float)xh);
      aZRh[el256(row, 64 + cy)] = (f16)mv;
    }
  }
  __syncthreads();

  // ---------- main loop ----------
#pragma unroll 1
  for (int t = 0; t < kT; ++t) {
    const int tc = (t + 1 < kT) ? (t + 1) : (kT - 1);

    // prefetch next-step inputs (consumed post-B1 / in GAMMA; L2-resident lines)
    float dv[16], xv[4], mv[4];
#pragma unroll
    for (int q = 0; q < 2; ++q)
#pragma unroll
      for (int e = 0; e < 8; ++e) dv[q * 8 + e] = gIn[dBase + (size_t)(q * 32 + kg * 8 + e) * kT + tc];
#pragma unroll
    for (int rr = 0; rr < 4; ++rr) { xv[rr] = gIn[xB[rr] + tc]; mv[rr] = gIn[mB[rr] + tc]; }

    // ---- ALPHA: z, r, HA (hi+lo split), y(t-1) ----
    f32x4 accZ[2], accR[2], accHA[2], accY;
    accZ[0] = zero4(); accZ[1] = zero4();
    accR[0] = zero4(); accR[1] = zero4();
    accHA[0] = zero4(); accHA[1] = zero4();
    accY = zero4();
#pragma unroll
    for (int ks = 0; ks < 8; ++ks) {
      const int base = fr256(lr, ks * 4 + kg);
      const f16x8 ah = *(const f16x8*)&aZRh[base];
      const f16x8 al = *(const f16x8*)&aZRl[base];
#pragma unroll
      for (int tz = 0; tz < 2; ++tz) {
        accZ[tz] = mm(al, wz[tz][ks],  accZ[tz]); accZ[tz] = mm(ah, wz[tz][ks],  accZ[tz]);
        accR[tz] = mm(al, wr_[tz][ks], accR[tz]); accR[tz] = mm(ah, wr_[tz][ks], accR[tz]);
        if (ks < 4) { accHA[tz] = mm(al, wha[tz][ks], accHA[tz]); accHA[tz] = mm(ah, wha[tz][ks], accHA[tz]); }
      }
    }
    if (t > 0) {
#pragma unroll
      for (int ks = 0; ks < 4; ++ks) {
        const f16x8 fh = *(const f16x8*)&aH[fr128(lr, ks * 4 + kg)];
        accY = mm(fh, why_[ks], accY);
      }
    }

    // ---- BETA: gates, srh publish, y(t-1) store ----
    float zg[2][4];
#pragma unroll
    for (int tz = 0; tz < 2; ++tz)
#pragma unroll
      for (int rr = 0; rr < 4; ++rr) {
        const int row = kg * 4 + rr, j = 32 * w + 16 * tz + lr;
        zg[tz][rr] = sigm(accZ[tz][rr] + bz[tz]);
        const float rq = sigm(accR[tz][rr]);         // r has no bias
        aSRH[el128(row, j)] = (f16)(rq * ghh[tz][rr]);
      }
    if (t > 0) {
#pragma unroll
      for (int rr = 0; rr < 4; ++rr)
        out[yB[rr] + (size_t)(t - 1) * kOut] = sigm(accY[rr] + by);
    }
    __syncthreads();   // B1: srh visible

    // ---- HH + dgh/dgx for t+1 ----
    f32x4 accHH[2]; accHH[0] = zero4(); accHH[1] = zero4();
#pragma unroll
    for (int ks = 0; ks < 4; ++ks) {
      const f16x8 fs = *(const f16x8*)&aSRH[fr128(lr, ks * 4 + kg)];
      accHH[0] = mm(fs, whh[0][ks], accHH[0]);
      accHH[1] = mm(fs, whh[1][ks], accHH[1]);
    }
    f16x8 fd[2];
#pragma unroll
    for (int q = 0; q < 2; ++q)
#pragma unroll
      for (int e = 0; e < 8; ++e) fd[q][e] = (f16)dv[q * 8 + e];
    f32x4 accG[2], accX;
    accG[0] = zero4(); accG[1] = zero4(); accX = zero4();
#pragma unroll
    for (int q = 0; q < 2; ++q) {
      accG[0] = mm(fd[q], wdgh[0][q], accG[0]);
      accG[1] = mm(fd[q], wdgh[1][q], accG[1]);
      accX    = mm(fd[q], wdgx[q],    accX);
    }

    // ---- GAMMA: h update + publishes for t+1 ----
#pragma unroll
    for (int tz = 0; tz < 2; ++tz)
#pragma unroll
      for (int rr = 0; rr < 4; ++rr) {
        const int row = kg * 4 + rr, j = 32 * w + 16 * tz + lr;
        const float ht = tanh_(accHA[tz][rr] + accHH[tz][rr] + bh[tz]);
        const float z  = zg[tz][rr];
        const float hn = (1.f - z) * ghh[tz][rr] + z * ht;
        out[hB[rr] + (size_t)t * kHid + j] = hn;
        aH[el128(row, j)] = (f16)hn;
        const float gh = __expf(-fmaxf(accG[tz][rr] + bgh[tz], 0.f));
        const float gv = gh * hn;                    // gh(t+1) * h(t)
        ghh[tz][rr] = gv;
        const f16 gvh = (f16)gv;
        aZRh[el256(row, 128 + j)] = gvh;
        aZRl[el256(row, 128 + j)] = (f16)(gv - (float)gvh);
      }
#pragma unroll
    for (int rr = 0; rr < 4; ++rr) {                 // x'(t+1), m(t+1)
      const int row = kg * 4 + rr;
      const float gx = __expf(-fmaxf(accX[rr] + bgx, 0.f));
      xl[rr] = (mv[rr] > 0.f) ? xv[rr] : xl[rr];
      const float xp = mv[rr] * xv[rr] + (1.f - mv[rr]) * (gx * xl[rr] + (1.f - gx) * xmn);
      const f16 xh = (f16)xp;
      aZRh[el256(row, cy)]      = xh;
      aZRl[el256(row, cy)]      = (f16)(xp - (float)xh);
      aZRh[el256(row, 64 + cy)] = (f16)mv[rr];
    }
    __syncthreads();   // B2: aZR/aH for t+1 visible
  }

  // ---------- epilogue: y(999) ----------
  {
    f32x4 accY = zero4();
#pragma unroll
    for (int ks = 0; ks < 4; ++ks) {
      const f16x8 fh = *(const f16x8*)&aH[fr128(lr, ks * 4 + kg)];
      accY = mm(fh, why_[ks], accY);
    }
#pragma unroll
    for (int rr = 0; rr < 4; ++rr)
      out[yB[rr] + (size_t)(kT - 1) * kOut] = sigm(accY[rr] + by);
  }
}

} // namespace

extern "C" void kernel_launch(void* const* d_in, const int* in_sizes, int n_in,
                              void* d_out, int out_size, void* d_ws, size_t ws_size,
                              hipStream_t stream) {
  const float* gIn   = (const float*)d_in[0];
  const float* xMean = (const float*)d_in[1];
  const float* Wdgx  = (const float*)d_in[2];
  const float* bdgx  = (const float*)d_in[3];
  const float* Wdgh  = (const float*)d_in[4];
  const float* bdgh  = (const float*)d_in[5];
  const float* Wxz   = (const float*)d_in[6];
  const float* Whz   = (const float*)d_in[7];
  const float* Wmz   = (const float*)d_in[8];
  const float* bmz   = (const float*)d_in[9];
  const float* Wxr   = (const float*)d_in[10];
  const float* Whr   = (const float*)d_in[11];
  const float* Wmr   = (const float*)d_in[12];
  const float* Wxh   = (const float*)d_in[13];
  const float* Whh   = (const float*)d_in[14];
  const float* Wmh   = (const float*)d_in[15];
  const float* bmh   = (const float*)d_in[16];
  const float* Why   = (const float*)d_in[17];
  const float* bhy   = (const float*)d_in[18];

  grud_mfma<<<dim3(kBatch / kRows), dim3(256), 0, stream>>>(
      gIn, xMean, Wdgx, bdgx, Wdgh, bdgh, Wxz, Whz, Wmz, bmz,
      Wxr, Whr, Wmr, Wxh, Whh, Wmh, bmh, Why, bhy, (float*)d_out);
}

// Round 5
// 5136.091 us; speedup vs baseline: 1.0953x; 1.0953x over previous
//
#include <hip/hip_runtime.h>
#include <hip/hip_fp16.h>

namespace {

typedef _Float16 f16;
typedef __attribute__((ext_vector_type(8))) _Float16 f16x8;
typedef __attribute__((ext_vector_type(4))) float f32x4;

constexpr int kIn     = 64;
constexpr int kHid    = 128;
constexpr int kOut    = 64;
constexpr int kT      = 1000;
constexpr int kBatch  = 256;
constexpr int kRows   = 16;    // batch rows per block (MFMA M dimension)
constexpr int kChunks = kT / 8;

__device__ __forceinline__ float sigm(float v)  { return 1.0f / (1.0f + __expf(-v)); }
__device__ __forceinline__ float tanh_(float v) { return 2.0f / (1.0f + __expf(-2.0f * v)) - 1.0f; }

__device__ __forceinline__ f32x4 zero4() { f32x4 v; v[0]=0.f; v[1]=0.f; v[2]=0.f; v[3]=0.f; return v; }

__device__ __forceinline__ f32x4 mm(f16x8 a, f16x8 b, f32x4 c) {
  return __builtin_amdgcn_mfma_f32_16x16x32_f16(a, b, c, 0, 0, 0);
}

// LDS activation tiles [16 rows][K] f16, 16B-chunk XOR-swizzled by row.
__device__ __forceinline__ int fr256(int row, int chunk) { return row*256 + ((chunk ^ (row & 7)) << 3); }
__device__ __forceinline__ int fr128(int row, int chunk) { return row*128 + ((chunk ^ (row & 7)) << 3); }
__device__ __forceinline__ int fr64 (int row, int chunk) { return row*64  + ((chunk ^ (row & 7)) << 3); }
__device__ __forceinline__ int el256(int row, int k) { return row*256 + ((((k >> 3) ^ (row & 7)) << 3) | (k & 7)); }
__device__ __forceinline__ int el128(int row, int k) { return row*128 + ((((k >> 3) ^ (row & 7)) << 3) | (k & 7)); }
__device__ __forceinline__ int el64 (int row, int k) { return row*64  + ((((k >> 3) ^ (row & 7)) << 3) | (k & 7)); }

// 16 blocks x 256 threads (4 waves, 1 wave/EU -> big VGPR budget, proven r2/r4).
// Inputs are register-chunked: once per 8 steps each lane loads its d/x/m slice
// with t-contiguous float4 (coalesced-per-line, fully consumed) -> no per-step
// global loads on the barrier-drain path.
__global__ __attribute__((amdgpu_flat_work_group_size(256, 256),
                          amdgpu_waves_per_eu(1, 1)))
void grud_mfma(
    const float* __restrict__ gIn,
    const float* __restrict__ xMean,
    const float* __restrict__ Wdgx, const float* __restrict__ bdgx,
    const float* __restrict__ Wdgh, const float* __restrict__ bdgh,
    const float* __restrict__ Wxz,  const float* __restrict__ Whz,
    const float* __restrict__ Wmz,  const float* __restrict__ bmz,
    const float* __restrict__ Wxr,  const float* __restrict__ Whr,
    const float* __restrict__ Wmr,
    const float* __restrict__ Wxh,  const float* __restrict__ Whh,
    const float* __restrict__ Wmh,  const float* __restrict__ bmh,
    const float* __restrict__ Why,  const float* __restrict__ bhy,
    float* __restrict__ out)
{
  // activations: [x'|m|gh*h] K=256 hi, x'-lo K=64, srh K=128, h K=128
  __shared__ __align__(16) f16 aZRh[kRows * 256];
  __shared__ __align__(16) f16 aXl [kRows * 64];
  __shared__ __align__(16) f16 aSRH[kRows * 128];
  __shared__ __align__(16) f16 aH  [kRows * 128];

  const int tid = threadIdx.x;
  const int w   = tid >> 6;        // wave 0..3
  const int l   = tid & 63;
  const int lr  = l & 15;          // fragment row/col index
  const int kg  = l >> 4;          // k-group 0..3
  const int b0  = blockIdx.x * kRows;

  auto ldB = [&](const float* W, int N, int kb, int jb) {
    f16x8 v;
#pragma unroll
    for (int e = 0; e < 8; ++e) v[e] = (f16)W[(kb + kg * 8 + e) * N + jb + lr];
    return v;
  };

  // ---------- weights in VGPRs (layouts verified on HW in r4) ----------
  f16x8 wz[2][8], wr_[2][8], wha[2][4], whh[2][4], wdgh[2][2], wdgx[2], why_[4];
#pragma unroll
  for (int tz = 0; tz < 2; ++tz) {
    const int jb = 32 * w + 16 * tz;
#pragma unroll
    for (int ks = 0; ks < 8; ++ks) {           // z/r: K=256 concat [x'|m|gh*h]
      const int kb = ks * 32;
      const float* Wzp = (kb < 64) ? Wxz : ((kb < 128) ? Wmz : Whz);
      const float* Wrp = (kb < 64) ? Wxr : ((kb < 128) ? Wmr : Whr);
      const int ko = (kb < 64) ? kb : ((kb < 128) ? (kb - 64) : (kb - 128));
      wz [tz][ks] = ldB(Wzp, kHid, ko, jb);
      wr_[tz][ks] = ldB(Wrp, kHid, ko, jb);
    }
#pragma unroll
    for (int ks = 0; ks < 4; ++ks) {           // HA: K=128 [x'|m]; HH: K=128
      const int kb = ks * 32;
      wha[tz][ks] = ldB((kb < 64) ? Wxh : Wmh, kHid, (kb < 64) ? kb : (kb - 64), jb);
      whh[tz][ks] = ldB(Whh, kHid, kb, jb);
    }
    wdgh[tz][0] = ldB(Wdgh, kHid, 0,  jb);
    wdgh[tz][1] = ldB(Wdgh, kHid, 32, jb);
  }
  wdgx[0] = ldB(Wdgx, kIn, 0,  16 * w);
  wdgx[1] = ldB(Wdgx, kIn, 32, 16 * w);
#pragma unroll
  for (int ks = 0; ks < 4; ++ks) why_[ks] = ldB(Why, kOut, ks * 32, 16 * w);

  // ---------- lane-local constants ----------
  const int   j0 = 32 * w + lr, j1 = j0 + 16;
  const float bz[2]  = {bmz[j0],  bmz[j1]};
  const float bh[2]  = {bmh[j0],  bmh[j1]};
  const float bgh[2] = {bdgh[j0], bdgh[j1]};
  const int   cy  = 16 * w + lr;
  const float by  = bhy[cy], bgx = bdgx[cy], xmn = xMean[cy];

  const size_t dBase = ((size_t)(b0 + lr) * 3 + 2) * (size_t)(kIn * kT);
  size_t xB[4], mB[4], yB[4], hB[4];
#pragma unroll
  for (int rr = 0; rr < 4; ++rr) {
    const int row = kg * 4 + rr;
    xB[rr] = ((size_t)(b0 + row) * 3 + 0) * (size_t)(kIn * kT) + (size_t)cy * kT;
    mB[rr] = ((size_t)(b0 + row) * 3 + 1) * (size_t)(kIn * kT) + (size_t)cy * kT;
    yB[rr] = (size_t)(b0 + row) * kT * kOut + cy;
    hB[rr] = (size_t)kBatch * kT * kOut + (size_t)(b0 + row) * kT * kHid;
  }

  // ---------- register-chunked inputs (8 timesteps) ----------
  f16x8    dch[8][2];     // [t-slot][q]: A-fragment halves for d
  float    xch[4][8];     // [rr][t-slot]
  unsigned mbits = 0;     // bit rr*8+slot = (m>0)

  auto loadChunk = [&](int c) {
    const int t0 = c * 8;
#pragma unroll
    for (int q = 0; q < 2; ++q)
#pragma unroll
      for (int e = 0; e < 8; ++e) {
        const float* p = gIn + dBase + (size_t)(q * 32 + kg * 8 + e) * kT + t0;
        const float4 a = *(const float4*)p;
        const float4 b2 = *(const float4*)(p + 4);
        dch[0][q][e] = (f16)a.x;  dch[1][q][e] = (f16)a.y;
        dch[2][q][e] = (f16)a.z;  dch[3][q][e] = (f16)a.w;
        dch[4][q][e] = (f16)b2.x; dch[5][q][e] = (f16)b2.y;
        dch[6][q][e] = (f16)b2.z; dch[7][q][e] = (f16)b2.w;
      }
    unsigned mb = 0;
#pragma unroll
    for (int rr = 0; rr < 4; ++rr) {
      const float* px = gIn + xB[rr] + t0;
      const float4 xa = *(const float4*)px;
      const float4 xb = *(const float4*)(px + 4);
      xch[rr][0] = xa.x; xch[rr][1] = xa.y; xch[rr][2] = xa.z; xch[rr][3] = xa.w;
      xch[rr][4] = xb.x; xch[rr][5] = xb.y; xch[rr][6] = xb.z; xch[rr][7] = xb.w;
      const float* pm = gIn + mB[rr] + t0;
      const float4 ma = *(const float4*)pm;
      const float4 mb2 = *(const float4*)(pm + 4);
      mb |= (ma.x  > 0.f ? 1u : 0u) << (rr * 8 + 0);
      mb |= (ma.y  > 0.f ? 1u : 0u) << (rr * 8 + 1);
      mb |= (ma.z  > 0.f ? 1u : 0u) << (rr * 8 + 2);
      mb |= (ma.w  > 0.f ? 1u : 0u) << (rr * 8 + 3);
      mb |= (mb2.x > 0.f ? 1u : 0u) << (rr * 8 + 4);
      mb |= (mb2.y > 0.f ? 1u : 0u) << (rr * 8 + 5);
      mb |= (mb2.z > 0.f ? 1u : 0u) << (rr * 8 + 6);
      mb |= (mb2.w > 0.f ? 1u : 0u) << (rr * 8 + 7);
    }
    mbits = mb;
  };

  // ---------- init ----------
  for (int i = tid; i < kRows * 256; i += 256) aZRh[i] = (f16)0.f;
  for (int i = tid; i < kRows * 64;  i += 256) aXl[i]  = (f16)0.f;
  for (int i = tid; i < kRows * 128; i += 256) { aSRH[i] = (f16)0.f; aH[i] = (f16)0.f; }
  __syncthreads();

  float ghh[2][4]  = {};   // gh(t)*h(t-1), lane-local
  float xl[4]      = {};   // last-observed x
  float hstv[2][4] = {};   // h(t-1) awaiting store

  // ---------- prologue: chunk 0 + x'(0)/m(0) publish ----------
  loadChunk(0);
  {
    f32x4 aX = zero4();
    aX = mm(dch[0][0], wdgx[0], aX);
    aX = mm(dch[0][1], wdgx[1], aX);
#pragma unroll
    for (int rr = 0; rr < 4; ++rr) {
      const int row = kg * 4 + rr;
      const bool mbit = (mbits >> (rr * 8)) & 1u;
      const float xv = xch[rr][0];
      const float gx = __expf(-fmaxf(aX[rr] + bgx, 0.f));
      xl[rr] = mbit ? xv : 0.f;
      const float xp = mbit ? xv : (gx * xl[rr] + (1.f - gx) * xmn);
      const f16 xh = (f16)xp;
      aZRh[el256(row, cy)]      = xh;
      aXl [el64 (row, cy)]      = (f16)(xp - (float)xh);
      aZRh[el256(row, 64 + cy)] = mbit ? (f16)1.f : (f16)0.f;
    }
  }
  __syncthreads();

  // ---------- main loop: chunks x 8 unrolled steps ----------
#pragma unroll 1
  for (int c = 0; c < kChunks; ++c) {
#pragma unroll
    for (int tt = 0; tt < 8; ++tt) {
      const int t = 8 * c + tt;
      const int sn = (tt + 1) & 7;   // next-step slot (compile-time)

      // ---- ALPHA: h(t-1) store; z/r/HA MFMAs; y(t-1) MFMA ----
      if (t > 0) {
#pragma unroll
        for (int tz = 0; tz < 2; ++tz)
#pragma unroll
          for (int rr = 0; rr < 4; ++rr)
            out[hB[rr] + (size_t)(t - 1) * kHid + (32 * w + 16 * tz + lr)] = hstv[tz][rr];
      }
      f32x4 accZ[2], accR[2], accHA[2], accY;
      accZ[0] = zero4(); accZ[1] = zero4();
      accR[0] = zero4(); accR[1] = zero4();
      accHA[0] = zero4(); accHA[1] = zero4();
      accY = zero4();
#pragma unroll
      for (int ks = 0; ks < 8; ++ks) {
        const f16x8 ah = *(const f16x8*)&aZRh[fr256(lr, ks * 4 + kg)];
#pragma unroll
        for (int tz = 0; tz < 2; ++tz) {
          accZ[tz] = mm(ah, wz[tz][ks],  accZ[tz]);
          accR[tz] = mm(ah, wr_[tz][ks], accR[tz]);
          if (ks < 4) accHA[tz] = mm(ah, wha[tz][ks], accHA[tz]);
        }
      }
#pragma unroll
      for (int ks = 0; ks < 2; ++ks) {     // x'-lo correction
        const f16x8 al = *(const f16x8*)&aXl[fr64(lr, ks * 4 + kg)];
#pragma unroll
        for (int tz = 0; tz < 2; ++tz) {
          accZ[tz]  = mm(al, wz[tz][ks],  accZ[tz]);
          accR[tz]  = mm(al, wr_[tz][ks], accR[tz]);
          accHA[tz] = mm(al, wha[tz][ks], accHA[tz]);
        }
      }
      if (t > 0) {
#pragma unroll
        for (int ks = 0; ks < 4; ++ks) {
          const f16x8 fh = *(const f16x8*)&aH[fr128(lr, ks * 4 + kg)];
          accY = mm(fh, why_[ks], accY);
        }
      }

      // ---- BETA: gates + srh publish ----
      float zg[2][4];
#pragma unroll
      for (int tz = 0; tz < 2; ++tz)
#pragma unroll
        for (int rr = 0; rr < 4; ++rr) {
          const int row = kg * 4 + rr, j = 32 * w + 16 * tz + lr;
          zg[tz][rr] = sigm(accZ[tz][rr] + bz[tz]);
          const float rq = sigm(accR[tz][rr]);
          aSRH[el128(row, j)] = (f16)(rq * ghh[tz][rr]);
        }
      __syncthreads();   // B1

      // ---- HH + gamma(t+1) MFMAs; y(t-1) store ----
      f32x4 accHH[2]; accHH[0] = zero4(); accHH[1] = zero4();
#pragma unroll
      for (int ks = 0; ks < 4; ++ks) {
        const f16x8 fs = *(const f16x8*)&aSRH[fr128(lr, ks * 4 + kg)];
        accHH[0] = mm(fs, whh[0][ks], accHH[0]);
        accHH[1] = mm(fs, whh[1][ks], accHH[1]);
      }
      f32x4 accG[2], accX;
      accG[0] = zero4(); accG[1] = zero4(); accX = zero4();
#pragma unroll
      for (int q = 0; q < 2; ++q) {
        accG[0] = mm(dch[sn][q], wdgh[0][q], accG[0]);
        accG[1] = mm(dch[sn][q], wdgh[1][q], accG[1]);
        accX    = mm(dch[sn][q], wdgx[q],    accX);
      }
      if (t > 0) {
#pragma unroll
        for (int rr = 0; rr < 4; ++rr)
          out[yB[rr] + (size_t)(t - 1) * kOut] = sigm(accY[rr] + by);
      }

      // ---- GAMMA: h update + t+1 publishes ----
#pragma unroll
      for (int tz = 0; tz < 2; ++tz)
#pragma unroll
        for (int rr = 0; rr < 4; ++rr) {
          const int row = kg * 4 + rr, j = 32 * w + 16 * tz + lr;
          const float ht = tanh_(accHA[tz][rr] + accHH[tz][rr] + bh[tz]);
          const float z  = zg[tz][rr];
          const float hn = (1.f - z) * ghh[tz][rr] + z * ht;
          hstv[tz][rr] = hn;
          aH[el128(row, j)] = (f16)hn;
          const float gh = __expf(-fmaxf(accG[tz][rr] + bgh[tz], 0.f));
          const float gv = gh * hn;                    // gh(t+1) * h(t)
          ghh[tz][rr] = gv;
          aZRh[el256(row, 128 + j)] = (f16)gv;
        }
#pragma unroll
      for (int rr = 0; rr < 4; ++rr) {                 // x'(t+1), m(t+1)
        const int row = kg * 4 + rr;
        const bool mbit = (mbits >> (rr * 8 + sn)) & 1u;
        const float xv = xch[rr][sn];
        const float gx = __expf(-fmaxf(accX[rr] + bgx, 0.f));
        xl[rr] = mbit ? xv : xl[rr];
        const float xp = mbit ? xv : (gx * xl[rr] + (1.f - gx) * xmn);
        const f16 xh = (f16)xp;
        aZRh[el256(row, cy)]      = xh;
        aXl [el64 (row, cy)]      = (f16)(xp - (float)xh);
        aZRh[el256(row, 64 + cy)] = mbit ? (f16)1.f : (f16)0.f;
      }

      if (tt == 6 && c + 1 < kChunks) loadChunk(c + 1);
      __syncthreads();   // B2
    }
  }

  // ---------- epilogue: h(999), y(999) ----------
#pragma unroll
  for (int tz = 0; tz < 2; ++tz)
#pragma unroll
    for (int rr = 0; rr < 4; ++rr)
      out[hB[rr] + (size_t)(kT - 1) * kHid + (32 * w + 16 * tz + lr)] = hstv[tz][rr];
  {
    f32x4 accY = zero4();
#pragma unroll
    for (int ks = 0; ks < 4; ++ks) {
      const f16x8 fh = *(const f16x8*)&aH[fr128(lr, ks * 4 + kg)];
      accY = mm(fh, why_[ks], accY);
    }
#pragma unroll
    for (int rr = 0; rr < 4; ++rr)
      out[yB[rr] + (size_t)(kT - 1) * kOut] = sigm(accY[rr] + by);
  }
}

} // namespace

extern "C" void kernel_launch(void* const* d_in, const int* in_sizes, int n_in,
                              void* d_out, int out_size, void* d_ws, size_t ws_size,
                              hipStream_t stream) {
  const float* gIn   = (const float*)d_in[0];
  const float* xMean = (const float*)d_in[1];
  const float* Wdgx  = (const float*)d_in[2];
  const float* bdgx  = (const float*)d_in[3];
  const float* Wdgh  = (const float*)d_in[4];
  const float* bdgh  = (const float*)d_in[5];
  const float* Wxz   = (const float*)d_in[6];
  const float* Whz   = (const float*)d_in[7];
  const float* Wmz   = (const float*)d_in[8];
  const float* bmz   = (const float*)d_in[9];
  const float* Wxr   = (const float*)d_in[10];
  const float* Whr   = (const float*)d_in[11];
  const float* Wmr   = (const float*)d_in[12];
  const float* Wxh   = (const float*)d_in[13];
  const float* Whh   = (const float*)d_in[14];
  const float* Wmh   = (const float*)d_in[15];
  const float* bmh   = (const float*)d_in[16];
  const float* Why   = (const float*)d_in[17];
  const float* bhy   = (const float*)d_in[18];

  grud_mfma<<<dim3(kBatch / kRows), dim3(256), 0, stream>>>(
      gIn, xMean, Wdgx, bdgx, Wdgh, bdgh, Wxz, Whz, Wmz, bmz,
      Wxr, Whr, Wmr, Wxh, Whh, Wmh, bmh, Why, bhy, (float*)d_out);
}